// Round 10
// baseline (86.993 us; speedup 1.0000x reference)
//
#include <hip/hip_runtime.h>

typedef __attribute__((ext_vector_type(8))) short bf16x8;
typedef __attribute__((ext_vector_type(4))) float f32x4;

constexpr int N       = 50000;
constexpr int NE      = 800000;
constexpr int AD      = 128;   // ATOM_DIM
constexpr int BD      = 16;    // BOND_DIM
constexpr int BD2     = 256;   // BD*BD
constexpr int HIDDEN  = 128;
constexpr int NB      = 64;    // nodes per block
constexpr int SSTR    = 20;    // S/exchange LDS stride (floats)
constexpr int OSTR    = 132;   // out repack stride (floats)

// f32 -> bf16 round-to-nearest-even
__device__ inline short f2bf(float f) {
    union U { float f; unsigned u; } v; v.f = f;
    unsigned r = v.u + 0x7fffu + ((v.u >> 16) & 1u);
    return (short)(r >> 16);
}

// ---------------------------------------------------------------------------
// Kernel 0: build bf16 fragment-linear operand tables (kmat, Wn|Wi padded).
// ---------------------------------------------------------------------------
__global__ __launch_bounds__(256) void prep_frags(
    const float* __restrict__ kmat,
    const float* __restrict__ Wn,
    const float* __restrict__ Wi,
    short* __restrict__ kbf,
    short* __restrict__ wbf)
{
    int t = blockIdx.x * 256 + threadIdx.x;
    if (t < 4096) {
        int u = t >> 6, l = t & 63;
        int nf = u >> 2, kk = u & 3;
        int col = nf * 16 + (l & 15);
        int k0  = kk * 32 + (l >> 4) * 8;
        bf16x8 o;
#pragma unroll
        for (int j = 0; j < 8; ++j) o[j] = f2bf(kmat[(size_t)(k0 + j) * BD2 + col]);
        *(bf16x8*)(kbf + (size_t)t * 8) = o;
    } else if (t < 4096 + 1024) {
        int t2 = t - 4096;
        int u = t2 >> 6, l = t2 & 63;
        int m = u >> 3, nf2 = u & 7;
        const float* W = m ? Wi : Wn;
        int col = nf2 * 16 + (l & 15);
        int k0  = (l >> 4) * 8;
        bf16x8 o;
#pragma unroll
        for (int j = 0; j < 8; ++j) {
            int k = k0 + j;
            o[j] = (k < 16) ? f2bf(W[(size_t)k * HIDDEN + col]) : (short)0;
        }
        *(bf16x8*)(wbf + (size_t)t2 * 8) = o;
    }
}

// ---------------------------------------------------------------------------
// Kernel 1: scatter + GEMM + S-contraction, one block = 64 nodes.
//  - kbf fragments prefetched into registers up-front (16 independent loads
//    in flight during the scatter phase -> no load->MFMA dependent chain)
//  - edge range by validated windowed binary search (pairs sorted by src)
//  - S built in LDS (never touches global)
//  - nf-split GEMM: wave w computes output cols 4w..4w+3, 4x B reuse
//  - writes only agg (N x 16, 3.2MB)
// ---------------------------------------------------------------------------
__global__ __launch_bounds__(256, 3) void gemm_scatter(
    const float* __restrict__ atoms,
    const float* __restrict__ bonds,
    const int*  __restrict__ pairs,
    const short* __restrict__ kbf,    // 64KB fragment-linear kmat
    const float* __restrict__ bias,   // 256
    float* __restrict__ agg)          // N x 16 out
{
    __shared__ float st[NB * SSTR];   // 5KB: S tile, then agg exchange

    const int tid = threadIdx.x;
    const int w   = tid >> 6;
    const int l   = tid & 63;
    const int lq  = l >> 4;
    const int lj  = l & 15;
    const int nb  = blockIdx.x * NB;

    // ---- prefetch this wave's 16 B fragments (issued first, used last) ----
    const bf16x8* kb = (const bf16x8*)kbf;
    bf16x8 bfr[16];
#pragma unroll
    for (int i = 0; i < 16; ++i)
        bfr[i] = kb[(size_t)((w * 4 + (i >> 2)) * 4 + (i & 3)) * 64 + l];

    // ---- zero S tile ------------------------------------------------------
    for (int i = tid; i < NB * SSTR; i += 256) st[i] = 0.f;

    // ---- windowed binary search for edge range ----------------------------
    int wlo = nb * 16 - 4096; if (wlo < 0) wlo = 0;
    int whi = (nb + NB) * 16 + 4096; if (whi > NE) whi = NE;
    if (wlo > 0  && pairs[2 * wlo] >= nb)      wlo = 0;
    if (whi < NE && pairs[2 * whi] <  nb + NB) whi = NE;
    int eLo, eHi;
    {
        int s = wlo, e = whi;
        while (s < e) { int m = (s + e) >> 1; if (pairs[2 * m] < nb) s = m + 1; else e = m; }
        eLo = s;
    }
    {
        int s = eLo, e = whi;
        while (s < e) { int m = (s + e) >> 1; if (pairs[2 * m] < nb + NB) s = m + 1; else e = m; }
        eHi = s;
    }
    __syncthreads();   // zero done

    // ---- segment-sum into LDS S tile --------------------------------------
    {
        const int g = tid >> 4;      // 16 groups of 16 lanes
        const int c = tid & 15;
        const int nE = eHi - eLo;
        const int cg = (nE + 15) >> 4;
        int gs = eLo + g * cg;
        int ge = gs + cg; if (ge > eHi) ge = eHi;
        int cur = -1; float acc = 0.f;
        int e = gs;
        for (; e + 4 <= ge; e += 4) {
            int2 pb[4]; float vb[4];
#pragma unroll
            for (int i = 0; i < 4; ++i) pb[i] = *(const int2*)(pairs + 2 * (e + i));
#pragma unroll
            for (int i = 0; i < 4; ++i) vb[i] = bonds[(size_t)pb[i].y * BD + c];
#pragma unroll
            for (int i = 0; i < 4; ++i) {
                if (pb[i].x != cur) {
                    if (cur >= 0) atomicAdd(&st[(cur - nb) * SSTR + c], acc);
                    acc = 0.f; cur = pb[i].x;
                }
                acc += vb[i];
            }
        }
        for (; e < ge; ++e) {
            int2 p = *(const int2*)(pairs + 2 * e);
            float v = bonds[(size_t)p.y * BD + c];
            if (p.x != cur) {
                if (cur >= 0) atomicAdd(&st[(cur - nb) * SSTR + c], acc);
                acc = 0.f; cur = p.x;
            }
            acc += v;
        }
        if (cur >= 0) atomicAdd(&st[(cur - nb) * SSTR + c], acc);
    }
    __syncthreads();

    // ---- read S values, then free the tile for the exchange ---------------
    float4 sval[4];
#pragma unroll
    for (int ng = 0; ng < 4; ++ng)
        sval[ng] = *(const float4*)(&st[(ng * 16 + lj) * SSTR + lq * 4]);
    __syncthreads();

    // ---- bias fragments (hoisted) -----------------------------------------
    float4 bv[4];
#pragma unroll
    for (int nfl = 0; nfl < 4; ++nfl)
        bv[nfl] = *(const float4*)(bias + (w * 4 + nfl) * 16 + lq * 4);

    // ---- GEMM + contraction, streaming over 4 node-groups -----------------
    float aggf[4][4];   // [ng][nfl]
#pragma unroll
    for (int ng = 0; ng < 4; ++ng) {
        int arow = nb + ng * 16 + lj; if (arow >= N) arow = N - 1;
        const float* ap = atoms + (size_t)arow * AD + lq * 8;
        bf16x8 af[4];
#pragma unroll
        for (int kk = 0; kk < 4; ++kk) {
            float4 a0 = *(const float4*)(ap + kk * 32);
            float4 a1 = *(const float4*)(ap + kk * 32 + 4);
            bf16x8 t;
            t[0] = f2bf(a0.x); t[1] = f2bf(a0.y); t[2] = f2bf(a0.z); t[3] = f2bf(a0.w);
            t[4] = f2bf(a1.x); t[5] = f2bf(a1.y); t[6] = f2bf(a1.z); t[7] = f2bf(a1.w);
            af[kk] = t;
        }
        f32x4 acc[4];
#pragma unroll
        for (int nfl = 0; nfl < 4; ++nfl) acc[nfl] = (f32x4){0.f, 0.f, 0.f, 0.f};
#pragma unroll
        for (int kk = 0; kk < 4; ++kk) {
#pragma unroll
            for (int nfl = 0; nfl < 4; ++nfl)
                acc[nfl] = __builtin_amdgcn_mfma_f32_16x16x32_bf16(
                    bfr[nfl * 4 + kk], af[kk], acc[nfl], 0, 0, 0);
        }
#pragma unroll
        for (int nfl = 0; nfl < 4; ++nfl) {
            float q = (acc[nfl][0] + bv[nfl].x) * sval[ng].x
                    + (acc[nfl][1] + bv[nfl].y) * sval[ng].y
                    + (acc[nfl][2] + bv[nfl].z) * sval[ng].z
                    + (acc[nfl][3] + bv[nfl].w) * sval[ng].w;
            q += __shfl_xor(q, 16);
            q += __shfl_xor(q, 32);
            aggf[ng][nfl] = q;     // all 64 lanes hold the sum
        }
    }

    // ---- exchange: lane (lq,lj) provides col w*4+lq for node ng*16+lj -----
#pragma unroll
    for (int ng = 0; ng < 4; ++ng) {
        float v = aggf[ng][0];
        v = (lq == 1) ? aggf[ng][1] : v;
        v = (lq == 2) ? aggf[ng][2] : v;
        v = (lq == 3) ? aggf[ng][3] : v;
        st[(ng * 16 + lj) * SSTR + w * 4 + lq] = v;
    }
    __syncthreads();

    // ---- coalesced agg write ----------------------------------------------
    {
        int node = tid >> 2;
        int c4   = (tid & 3) * 4;
        if (nb + node < N) {
            f32x4 v = *(const f32x4*)(&st[node * SSTR + c4]);
            *(f32x4*)(agg + (size_t)(nb + node) * BD + c4) = v;
        }
    }
}

// ---------------------------------------------------------------------------
// Kernel 2: epilogue + store streaming. grid = (nblk, 4): blockIdx.y picks
// which of the 4 output copies this block writes (4x store-issue overlap,
// MFMA work recomputed - it's trivial).
//  E = relu(bonds@Wi); out = relu(agg@Wn + E)  via 16 MFMAs per wave,
//  LDS repack -> coalesced plain f32x4 stores.
// ---------------------------------------------------------------------------
__global__ __launch_bounds__(256) void epilogue_store(
    const float* __restrict__ agg,    // N x 16
    const float* __restrict__ bonds,  // N x 16
    const short* __restrict__ wbf,    // 16KB fragment-linear Wn|Wi
    float* __restrict__ out)          // 4 x N x 128
{
    __shared__ float lds[NB * OSTR];  // 33.8KB repack

    const int tid = threadIdx.x;
    const int w   = tid >> 6;
    const int l   = tid & 63;
    const int lq  = l >> 4;
    const int lj  = l & 15;
    const int nb  = blockIdx.x * NB;
    const int cp  = blockIdx.y;       // which output copy
    const int wrow = nb + w * 16;

    int arow = wrow + lj; if (arow >= N) arow = N - 1;

    bf16x8 agg_a  = (bf16x8){0,0,0,0,0,0,0,0};
    bf16x8 bond_a = (bf16x8){0,0,0,0,0,0,0,0};
    {
        int half = lq & 1;
        float4 g0 = *(const float4*)(agg   + (size_t)arow * BD + half * 8);
        float4 g1 = *(const float4*)(agg   + (size_t)arow * BD + half * 8 + 4);
        float4 b0 = *(const float4*)(bonds + (size_t)arow * BD + half * 8);
        float4 b1 = *(const float4*)(bonds + (size_t)arow * BD + half * 8 + 4);
        if (lq < 2) {
            agg_a[0] = f2bf(g0.x); agg_a[1] = f2bf(g0.y); agg_a[2] = f2bf(g0.z); agg_a[3] = f2bf(g0.w);
            agg_a[4] = f2bf(g1.x); agg_a[5] = f2bf(g1.y); agg_a[6] = f2bf(g1.z); agg_a[7] = f2bf(g1.w);
            bond_a[0] = f2bf(b0.x); bond_a[1] = f2bf(b0.y); bond_a[2] = f2bf(b0.z); bond_a[3] = f2bf(b0.w);
            bond_a[4] = f2bf(b1.x); bond_a[5] = f2bf(b1.y); bond_a[6] = f2bf(b1.z); bond_a[7] = f2bf(b1.w);
        }
    }

    const bf16x8* wb = (const bf16x8*)wbf;
#pragma unroll
    for (int nf2 = 0; nf2 < 8; ++nf2) {
        bf16x8 wn_f = wb[(size_t)nf2 * 64 + l];
        bf16x8 wi_f = wb[(size_t)(8 + nf2) * 64 + l];
        f32x4 e = __builtin_amdgcn_mfma_f32_16x16x32_bf16(
            bond_a, wi_f, (f32x4){0.f, 0.f, 0.f, 0.f}, 0, 0, 0);
        e[0] = fmaxf(e[0], 0.f); e[1] = fmaxf(e[1], 0.f);
        e[2] = fmaxf(e[2], 0.f); e[3] = fmaxf(e[3], 0.f);
        f32x4 o = __builtin_amdgcn_mfma_f32_16x16x32_bf16(agg_a, wn_f, e, 0, 0, 0);
#pragma unroll
        for (int r = 0; r < 4; ++r) {
            int nl = w * 16 + 4 * lq + r;
            lds[nl * OSTR + nf2 * 16 + lj] = fmaxf(o[r], 0.f);
        }
    }
    __syncthreads();

    // ---- coalesced f32x4 stores of THIS block's copy ----------------------
#pragma unroll
    for (int p = 0; p < 8; ++p) {
        int idx  = tid + 256 * p;
        int nl   = idx >> 5;
        int h4   = (idx & 31) * 4;
        int node = nb + nl;
        if (node < N) {
            f32x4 v = *(const f32x4*)(&lds[nl * OSTR + h4]);
            *(f32x4*)(out + ((size_t)cp * N + node) * HIDDEN + h4) = v;
        }
    }
}

// ---------------------------------------------------------------------------
extern "C" void kernel_launch(void* const* d_in, const int* in_sizes, int n_in,
                              void* d_out, int out_size, void* d_ws, size_t ws_size,
                              hipStream_t stream)
{
    const float* atoms = (const float*)d_in[0];
    const float* bonds = (const float*)d_in[1];
    const int*   pairs = (const int*)d_in[2];
    const float* kmat  = (const float*)d_in[3];
    const float* bias  = (const float*)d_in[4];
    const float* Wn    = (const float*)d_in[5];
    const float* Wi    = (const float*)d_in[6];
    float* out = (float*)d_out;

    short* kbf = (short*)d_ws;                   // 64KB
    short* wbf = kbf + 4096 * 8;                 // 16KB
    float* agg = (float*)(wbf + 1024 * 8);       // 3.2MB
    // total ws footprint: 3.28MB (proven safe)

    const int nblk = (N + NB - 1) / NB;          // 782

    prep_frags<<<20, 256, 0, stream>>>(kmat, Wn, Wi, kbf, wbf);
    gemm_scatter<<<nblk, 256, 0, stream>>>(atoms, bonds, pairs, kbf, bias, agg);
    epilogue_store<<<dim3(nblk, 4), 256, 0, stream>>>(agg, bonds, wbf, out);
}

// Round 11
// 85.060 us; speedup vs baseline: 1.0227x; 1.0227x over previous
//
#include <hip/hip_runtime.h>

typedef __attribute__((ext_vector_type(8))) short bf16x8;
typedef __attribute__((ext_vector_type(4))) float f32x4;

constexpr int N       = 50000;
constexpr int NE      = 800000;
constexpr int AD      = 128;   // ATOM_DIM
constexpr int BD      = 16;    // BOND_DIM
constexpr int BD2     = 256;   // BD*BD
constexpr int HIDDEN  = 128;
constexpr int NBS     = 32;    // nodes per scatter/gemm block
constexpr int NBE     = 64;    // nodes per epilogue block
constexpr int SSTR    = 20;    // S/exchange LDS stride (floats)
constexpr int OSTR    = 132;   // out repack stride (floats)

// f32 -> bf16 round-to-nearest-even
__device__ inline short f2bf(float f) {
    union U { float f; unsigned u; } v; v.f = f;
    unsigned r = v.u + 0x7fffu + ((v.u >> 16) & 1u);
    return (short)(r >> 16);
}

// ---------------------------------------------------------------------------
// Kernel 0: build bf16 fragment-linear operand tables (kmat, Wn|Wi padded).
// ---------------------------------------------------------------------------
__global__ __launch_bounds__(256) void prep_frags(
    const float* __restrict__ kmat,
    const float* __restrict__ Wn,
    const float* __restrict__ Wi,
    short* __restrict__ kbf,
    short* __restrict__ wbf)
{
    int t = blockIdx.x * 256 + threadIdx.x;
    if (t < 4096) {
        int u = t >> 6, l = t & 63;
        int nf = u >> 2, kk = u & 3;
        int col = nf * 16 + (l & 15);
        int k0  = kk * 32 + (l >> 4) * 8;
        bf16x8 o;
#pragma unroll
        for (int j = 0; j < 8; ++j) o[j] = f2bf(kmat[(size_t)(k0 + j) * BD2 + col]);
        *(bf16x8*)(kbf + (size_t)t * 8) = o;
    } else if (t < 4096 + 1024) {
        int t2 = t - 4096;
        int u = t2 >> 6, l = t2 & 63;
        int m = u >> 3, nf2 = u & 7;
        const float* W = m ? Wi : Wn;
        int col = nf2 * 16 + (l & 15);
        int k0  = (l >> 4) * 8;
        bf16x8 o;
#pragma unroll
        for (int j = 0; j < 8; ++j) {
            int k = k0 + j;
            o[j] = (k < 16) ? f2bf(W[(size_t)k * HIDDEN + col]) : (short)0;
        }
        *(bf16x8*)(wbf + (size_t)t2 * 8) = o;
    }
}

// ---------------------------------------------------------------------------
// Kernel 1: S tiles, 32 nodes/block (short serial chains, high occupancy).
// Binary search the block's edge range (pairs sorted by src), LDS
// segment-sum, coalesced tile write. Every S element written exactly once.
// ---------------------------------------------------------------------------
__global__ __launch_bounds__(256) void scatter_tile(
    const int*  __restrict__ pairs,
    const float* __restrict__ bonds,
    float* __restrict__ S)
{
    __shared__ float st[NBS * SSTR];   // 2.5KB

    const int tid = threadIdx.x;
    const int nb  = blockIdx.x * NBS;

    for (int i = tid; i < NBS * SSTR; i += 256) st[i] = 0.f;

    // windowed binary search (validated fallback to full range)
    int wlo = nb * 16 - 4096; if (wlo < 0) wlo = 0;
    int whi = (nb + NBS) * 16 + 4096; if (whi > NE) whi = NE;
    if (wlo > 0  && pairs[2 * wlo] >= nb)       wlo = 0;
    if (whi < NE && pairs[2 * whi] <  nb + NBS) whi = NE;
    int eLo, eHi;
    {
        int s = wlo, e = whi;
        while (s < e) { int m = (s + e) >> 1; if (pairs[2 * m] < nb) s = m + 1; else e = m; }
        eLo = s;
    }
    {
        int s = eLo, e = whi;
        while (s < e) { int m = (s + e) >> 1; if (pairs[2 * m] < nb + NBS) s = m + 1; else e = m; }
        eHi = s;
    }
    __syncthreads();   // zero done

    {
        const int g = tid >> 4;      // 16 groups of 16 lanes
        const int c = tid & 15;
        const int nE = eHi - eLo;
        const int cg = (nE + 15) >> 4;
        int gs = eLo + g * cg;
        int ge = gs + cg; if (ge > eHi) ge = eHi;
        int cur = -1; float acc = 0.f;
        int e = gs;
        for (; e + 4 <= ge; e += 4) {
            int2 pb[4]; float vb[4];
#pragma unroll
            for (int i = 0; i < 4; ++i) pb[i] = *(const int2*)(pairs + 2 * (e + i));
#pragma unroll
            for (int i = 0; i < 4; ++i) vb[i] = bonds[(size_t)pb[i].y * BD + c];
#pragma unroll
            for (int i = 0; i < 4; ++i) {
                if (pb[i].x != cur) {
                    if (cur >= 0) atomicAdd(&st[(cur - nb) * SSTR + c], acc);
                    acc = 0.f; cur = pb[i].x;
                }
                acc += vb[i];
            }
        }
        for (; e < ge; ++e) {
            int2 p = *(const int2*)(pairs + 2 * e);
            float v = bonds[(size_t)p.y * BD + c];
            if (p.x != cur) {
                if (cur >= 0) atomicAdd(&st[(cur - nb) * SSTR + c], acc);
                acc = 0.f; cur = p.x;
            }
            acc += v;
        }
        if (cur >= 0) atomicAdd(&st[(cur - nb) * SSTR + c], acc);
    }
    __syncthreads();

    // coalesced tile write: 128 threads x f32x4 = 32 nodes x 16 comps
    if (tid < NBS * 4) {
        int node = tid >> 2;
        int c4   = (tid & 3) * 4;
        if (nb + node < N) {
            f32x4 v = *(const f32x4*)(&st[node * SSTR + c4]);
            *(f32x4*)(S + (size_t)(nb + node) * BD + c4) = v;
        }
    }
}

// ---------------------------------------------------------------------------
// Kernel 2: GEMM + S-contraction, 32 nodes/block (2 node-groups), 4 waves,
// nf-split across waves (wave w: output cols 4w..4w+3, 2x B reuse, kbf
// loaded inline - L2-hot). High occupancy via (256,4). Writes agg only.
// ---------------------------------------------------------------------------
__global__ __launch_bounds__(256, 4) void gemm_contract(
    const float* __restrict__ atoms,
    const short* __restrict__ kbf,    // 64KB fragment-linear kmat
    const float* __restrict__ bias,   // 256
    const float* __restrict__ S,      // N x 16
    float* __restrict__ agg)          // N x 16
{
    __shared__ float ag[NBS * SSTR];  // 2.5KB exchange tile

    const int tid = threadIdx.x;
    const int w   = tid >> 6;
    const int l   = tid & 63;
    const int lq  = l >> 4;
    const int lj  = l & 15;
    const int nb  = blockIdx.x * NBS;

    // ---- A fragments + S for 2 node-groups (loads issued first) -----------
    bf16x8 afrag[2][4];   // [ng][kk]
    float4 sval[2];
#pragma unroll
    for (int ng = 0; ng < 2; ++ng) {
        int arow = nb + ng * 16 + lj; if (arow >= N) arow = N - 1;
        const float* ap = atoms + (size_t)arow * AD + lq * 8;
        sval[ng] = *(const float4*)(S + (size_t)arow * BD + lq * 4);
#pragma unroll
        for (int kk = 0; kk < 4; ++kk) {
            float4 a0 = *(const float4*)(ap + kk * 32);
            float4 a1 = *(const float4*)(ap + kk * 32 + 4);
            bf16x8 t;
            t[0] = f2bf(a0.x); t[1] = f2bf(a0.y); t[2] = f2bf(a0.z); t[3] = f2bf(a0.w);
            t[4] = f2bf(a1.x); t[5] = f2bf(a1.y); t[6] = f2bf(a1.z); t[7] = f2bf(a1.w);
            afrag[ng][kk] = t;
        }
    }

    // ---- per-nf: 4 B loads + 8 MFMAs + lane-local contraction -------------
    const bf16x8* kb = (const bf16x8*)kbf;
    float aggf[2][4];     // [ng][nfl]
#pragma unroll
    for (int nfl = 0; nfl < 4; ++nfl) {
        const int nf = w * 4 + nfl;
        bf16x8 b[4];
#pragma unroll
        for (int kk = 0; kk < 4; ++kk)
            b[kk] = kb[(size_t)(nf * 4 + kk) * 64 + l];
        f32x4 acc[2];
#pragma unroll
        for (int ng = 0; ng < 2; ++ng) acc[ng] = (f32x4){0.f, 0.f, 0.f, 0.f};
#pragma unroll
        for (int kk = 0; kk < 4; ++kk) {
#pragma unroll
            for (int ng = 0; ng < 2; ++ng)
                acc[ng] = __builtin_amdgcn_mfma_f32_16x16x32_bf16(
                    b[kk], afrag[ng][kk], acc[ng], 0, 0, 0);
        }
        float4 bv = *(const float4*)(bias + nf * 16 + lq * 4);
#pragma unroll
        for (int ng = 0; ng < 2; ++ng) {
            float q = (acc[ng][0] + bv.x) * sval[ng].x
                    + (acc[ng][1] + bv.y) * sval[ng].y
                    + (acc[ng][2] + bv.z) * sval[ng].z
                    + (acc[ng][3] + bv.w) * sval[ng].w;
            q += __shfl_xor(q, 16);
            q += __shfl_xor(q, 32);
            aggf[ng][nfl] = q;     // all 64 lanes hold the sum
        }
    }

    // ---- exchange: lane (lq,lj) provides col w*4+lq for node ng*16+lj -----
#pragma unroll
    for (int ng = 0; ng < 2; ++ng) {
        float v = aggf[ng][0];
        v = (lq == 1) ? aggf[ng][1] : v;
        v = (lq == 2) ? aggf[ng][2] : v;
        v = (lq == 3) ? aggf[ng][3] : v;
        ag[(ng * 16 + lj) * SSTR + w * 4 + lq] = v;
    }
    __syncthreads();

    if (tid < NBS * 4) {
        int node = tid >> 2;
        int c4   = (tid & 3) * 4;
        if (nb + node < N) {
            f32x4 v = *(const f32x4*)(&ag[node * SSTR + c4]);
            *(f32x4*)(agg + (size_t)(nb + node) * BD + c4) = v;
        }
    }
}

// ---------------------------------------------------------------------------
// Kernel 3: epilogue + store streaming, grid (nblk, 4): blockIdx.y picks the
// output copy (4x store-issue overlap, trivial MFMA work recomputed).
// ---------------------------------------------------------------------------
__global__ __launch_bounds__(256) void epilogue_store(
    const float* __restrict__ agg,    // N x 16
    const float* __restrict__ bonds,  // N x 16
    const short* __restrict__ wbf,    // 16KB fragment-linear Wn|Wi
    float* __restrict__ out)          // 4 x N x 128
{
    __shared__ float lds[NBE * OSTR];  // 33.8KB repack

    const int tid = threadIdx.x;
    const int w   = tid >> 6;
    const int l   = tid & 63;
    const int lq  = l >> 4;
    const int lj  = l & 15;
    const int nb  = blockIdx.x * NBE;
    const int cp  = blockIdx.y;
    const int wrow = nb + w * 16;

    int arow = wrow + lj; if (arow >= N) arow = N - 1;

    bf16x8 agg_a  = (bf16x8){0,0,0,0,0,0,0,0};
    bf16x8 bond_a = (bf16x8){0,0,0,0,0,0,0,0};
    {
        int half = lq & 1;
        float4 g0 = *(const float4*)(agg   + (size_t)arow * BD + half * 8);
        float4 g1 = *(const float4*)(agg   + (size_t)arow * BD + half * 8 + 4);
        float4 b0 = *(const float4*)(bonds + (size_t)arow * BD + half * 8);
        float4 b1 = *(const float4*)(bonds + (size_t)arow * BD + half * 8 + 4);
        if (lq < 2) {
            agg_a[0] = f2bf(g0.x); agg_a[1] = f2bf(g0.y); agg_a[2] = f2bf(g0.z); agg_a[3] = f2bf(g0.w);
            agg_a[4] = f2bf(g1.x); agg_a[5] = f2bf(g1.y); agg_a[6] = f2bf(g1.z); agg_a[7] = f2bf(g1.w);
            bond_a[0] = f2bf(b0.x); bond_a[1] = f2bf(b0.y); bond_a[2] = f2bf(b0.z); bond_a[3] = f2bf(b0.w);
            bond_a[4] = f2bf(b1.x); bond_a[5] = f2bf(b1.y); bond_a[6] = f2bf(b1.z); bond_a[7] = f2bf(b1.w);
        }
    }

    const bf16x8* wb = (const bf16x8*)wbf;
#pragma unroll
    for (int nf2 = 0; nf2 < 8; ++nf2) {
        bf16x8 wn_f = wb[(size_t)nf2 * 64 + l];
        bf16x8 wi_f = wb[(size_t)(8 + nf2) * 64 + l];
        f32x4 e = __builtin_amdgcn_mfma_f32_16x16x32_bf16(
            bond_a, wi_f, (f32x4){0.f, 0.f, 0.f, 0.f}, 0, 0, 0);
        e[0] = fmaxf(e[0], 0.f); e[1] = fmaxf(e[1], 0.f);
        e[2] = fmaxf(e[2], 0.f); e[3] = fmaxf(e[3], 0.f);
        f32x4 o = __builtin_amdgcn_mfma_f32_16x16x32_bf16(agg_a, wn_f, e, 0, 0, 0);
#pragma unroll
        for (int r = 0; r < 4; ++r) {
            int nl = w * 16 + 4 * lq + r;
            lds[nl * OSTR + nf2 * 16 + lj] = fmaxf(o[r], 0.f);
        }
    }
    __syncthreads();

#pragma unroll
    for (int p = 0; p < 8; ++p) {
        int idx  = tid + 256 * p;
        int nl   = idx >> 5;
        int h4   = (idx & 31) * 4;
        int node = nb + nl;
        if (node < N) {
            f32x4 v = *(const f32x4*)(&lds[nl * OSTR + h4]);
            *(f32x4*)(out + ((size_t)cp * N + node) * HIDDEN + h4) = v;
        }
    }
}

// ---------------------------------------------------------------------------
extern "C" void kernel_launch(void* const* d_in, const int* in_sizes, int n_in,
                              void* d_out, int out_size, void* d_ws, size_t ws_size,
                              hipStream_t stream)
{
    const float* atoms = (const float*)d_in[0];
    const float* bonds = (const float*)d_in[1];
    const int*   pairs = (const int*)d_in[2];
    const float* kmat  = (const float*)d_in[3];
    const float* bias  = (const float*)d_in[4];
    const float* Wn    = (const float*)d_in[5];
    const float* Wi    = (const float*)d_in[6];
    float* out = (float*)d_out;

    short* kbf  = (short*)d_ws;                   // 64KB
    short* wbf  = kbf + 4096 * 8;                 // 16KB
    float* Sagg = (float*)(wbf + 1024 * 8);       // 3.2MB (S, overwritten by agg in gemm)
    // total ws footprint: 3.28MB (proven safe)

    const int nblk32 = (N + NBS - 1) / NBS;       // 1563
    const int nblk64 = (N + NBE - 1) / NBE;       // 782

    prep_frags<<<20, 256, 0, stream>>>(kmat, Wn, Wi, kbf, wbf);
    scatter_tile<<<nblk32, 256, 0, stream>>>(pairs, bonds, Sagg);
    gemm_contract<<<nblk32, 256, 0, stream>>>(atoms, kbf, bias, Sagg, Sagg);
    epilogue_store<<<dim3(nblk64, 4), 256, 0, stream>>>(Sagg, bonds, wbf, out);
}